// Round 1
// baseline (3200.508 us; speedup 1.0000x reference)
//
#include <hip/hip_runtime.h>
#include <math.h>

#define FIN 35
#define F1  64
#define F2  2

// ---------- degree / norm ----------
__global__ void k_set_deg(float* deg, int n) {
    int i = blockIdx.x * blockDim.x + threadIdx.x;
    if (i < n) deg[i] = 1.0f;  // self-loop weight 1
}

__global__ void k_deg(const int* __restrict__ dst, const float* __restrict__ ew,
                      float* deg, int E) {
    int e = blockIdx.x * blockDim.x + threadIdx.x;
    if (e < E) atomicAdd(&deg[dst[e]], ew[e]);
}

__global__ void k_dinv(float* deg, int n) {
    int i = blockIdx.x * blockDim.x + threadIdx.x;
    if (i < n) {
        float d = deg[i];
        deg[i] = d > 0.0f ? rsqrtf(d) : 0.0f;
    }
}

// ---------- layer 1 GEMM: g1[row,f] = dinv[row] * sum_k x[row,k]*W1[k,f] ----------
__global__ void k_gemm1(const float* __restrict__ x, const float* __restrict__ W1,
                        const float* __restrict__ dinv, float* __restrict__ g1, int n) {
    __shared__ float W1s[FIN * F1];     // 2240 floats
    __shared__ float xs[4 * FIN];       // 140 floats
    int tid = threadIdx.x;
    for (int i = tid; i < FIN * F1; i += 256) W1s[i] = W1[i];
    int row0 = blockIdx.x * 4;
    int nrows = min(4, n - row0);
    if (tid < nrows * FIN) xs[tid] = x[(size_t)row0 * FIN + tid];
    __syncthreads();
    int rl = tid >> 6;          // 0..3
    int f  = tid & 63;
    if (rl < nrows) {
        float acc = 0.0f;
        #pragma unroll
        for (int k = 0; k < FIN; k++) acc += xs[rl * FIN + k] * W1s[k * F1 + f];
        int row = row0 + rl;
        g1[(size_t)row * F1 + f] = acc * dinv[row];
    }
}

// ---------- layer 1 scatter: tmp1[dst,:] += ew * g1[src,:]  (16 threads/edge, float4) ----------
__global__ void k_scatter1(const int* __restrict__ src, const int* __restrict__ dst,
                           const float* __restrict__ ew, const float* __restrict__ g1,
                           float* tmp1, int E) {
    long long t = (long long)blockIdx.x * blockDim.x + threadIdx.x;
    int e = (int)(t >> 4);
    if (e >= E) return;
    int q = (int)(t & 15);
    int s = src[e], d = dst[e];
    float w = ew[e];
    float4 v = *((const float4*)(g1 + (size_t)s * F1) + q);
    float* tp = tmp1 + (size_t)d * F1 + q * 4;
    atomicAdd(tp + 0, v.x * w);
    atomicAdd(tp + 1, v.y * w);
    atomicAdd(tp + 2, v.z * w);
    atomicAdd(tp + 3, v.w * w);
}

// ---------- layer 1 finalize: hrelu (in place into tmp1) ----------
__global__ void k_fin1(const float* __restrict__ g1, const float* __restrict__ dinv,
                       const float* __restrict__ b1, float* tmp1, int n) {
    int i = blockIdx.x * blockDim.x + threadIdx.x;
    if (i >= n * F1) return;
    int row = i >> 6, f = i & 63;
    float h = dinv[row] * (tmp1[i] + g1[i]) + b1[f];
    tmp1[i] = h > 0.0f ? h : 0.0f;
}

// ---------- layer 2 GEMM: g2[row,c] = dinv[row] * sum_k hrelu[row,k]*W2[k,c] ----------
__global__ void k_gemm2(const float* __restrict__ hrelu, const float* __restrict__ W2,
                        const float* __restrict__ dinv, float* __restrict__ g2, int n) {
    __shared__ float hs[64 * 65];   // +1 pad: avoid 32-way bank conflict on column reads
    __shared__ float W2s[F1 * F2];
    int tid = threadIdx.x;
    int row0 = blockIdx.x * 64;
    int nrows = min(64, n - row0);
    if (tid < F1 * F2) W2s[tid] = W2[tid];
    for (int idx = tid; idx < nrows * 64; idx += 256) {
        int r = idx >> 6, k = idx & 63;
        hs[r * 65 + k] = hrelu[(size_t)(row0 + r) * 64 + k];
    }
    __syncthreads();
    if (tid < nrows) {
        float a0 = 0.0f, a1 = 0.0f;
        #pragma unroll
        for (int k = 0; k < 64; k++) {
            float h = hs[tid * 65 + k];
            a0 += h * W2s[k * 2 + 0];
            a1 += h * W2s[k * 2 + 1];
        }
        int row = row0 + tid;
        float dv = dinv[row];
        g2[(size_t)row * 2 + 0] = a0 * dv;
        g2[(size_t)row * 2 + 1] = a1 * dv;
    }
}

// ---------- layer 2 scatter ----------
__global__ void k_scatter2(const int* __restrict__ src, const int* __restrict__ dst,
                           const float* __restrict__ ew, const float* __restrict__ g2,
                           float* tmp2, int E) {
    int e = blockIdx.x * blockDim.x + threadIdx.x;
    if (e >= E) return;
    int s = src[e], d = dst[e];
    float w = ew[e];
    float2 v = *(const float2*)(g2 + (size_t)s * 2);
    atomicAdd(tmp2 + (size_t)d * 2 + 0, v.x * w);
    atomicAdd(tmp2 + (size_t)d * 2 + 1, v.y * w);
}

// ---------- layer 2 finalize + log_softmax ----------
__global__ void k_fin2(const float* __restrict__ g2, const float* __restrict__ tmp2,
                       const float* __restrict__ dinv, const float* __restrict__ b2,
                       float* __restrict__ out, int n) {
    int i = blockIdx.x * blockDim.x + threadIdx.x;
    if (i >= n) return;
    float dv = dinv[i];
    float z0 = dv * (tmp2[i * 2 + 0] + g2[i * 2 + 0]) + b2[0];
    float z1 = dv * (tmp2[i * 2 + 1] + g2[i * 2 + 1]) + b2[1];
    float m = fmaxf(z0, z1);
    float lse = m + logf(expf(z0 - m) + expf(z1 - m));
    out[i * 2 + 0] = z0 - lse;
    out[i * 2 + 1] = z1 - lse;
}

extern "C" void kernel_launch(void* const* d_in, const int* in_sizes, int n_in,
                              void* d_out, int out_size, void* d_ws, size_t ws_size,
                              hipStream_t stream) {
    const float* x  = (const float*)d_in[0];
    const int*   ei = (const int*)d_in[1];     // [2, E] — src row then dst row
    const float* ew = (const float*)d_in[2];
    const float* W1 = (const float*)d_in[3];
    const float* b1 = (const float*)d_in[4];
    const float* W2 = (const float*)d_in[5];
    const float* b2 = (const float*)d_in[6];
    float* out = (float*)d_out;

    int n = in_sizes[0] / FIN;
    int E = in_sizes[2];
    const int* src = ei;
    const int* dst = ei + E;

    // workspace layout (floats): deg | g1 (n*64) | g2 (n*2) | tmp1 (n*64) | tmp2 (n*2)
    float* ws   = (float*)d_ws;
    float* deg  = ws;
    float* g1   = deg + n;
    float* g2   = g1 + (size_t)n * F1;
    float* tmp1 = g2 + (size_t)n * F2;
    float* tmp2 = tmp1 + (size_t)n * F1;

    // zero accumulators (tmp1,tmp2 contiguous: n*66 floats)
    hipMemsetAsync(tmp1, 0, (size_t)n * (F1 + F2) * sizeof(float), stream);

    k_set_deg<<<(n + 255) / 256, 256, 0, stream>>>(deg, n);
    k_deg<<<(E + 255) / 256, 256, 0, stream>>>(dst, ew, deg, E);
    k_dinv<<<(n + 255) / 256, 256, 0, stream>>>(deg, n);

    k_gemm1<<<(n + 3) / 4, 256, 0, stream>>>(x, W1, deg, g1, n);

    long long t1 = (long long)E * 16;
    k_scatter1<<<(int)((t1 + 255) / 256), 256, 0, stream>>>(src, dst, ew, g1, tmp1, E);
    k_fin1<<<(n * F1 + 255) / 256, 256, 0, stream>>>(g1, deg, b1, tmp1, n);

    k_gemm2<<<(n + 63) / 64, 256, 0, stream>>>(tmp1, W2, deg, g2, n);
    k_scatter2<<<(E + 255) / 256, 256, 0, stream>>>(src, dst, ew, g2, tmp2, E);
    k_fin2<<<(n + 255) / 256, 256, 0, stream>>>(g2, tmp2, deg, b2, out, n);
}

// Round 2
// 862.765 us; speedup vs baseline: 3.7096x; 3.7096x over previous
//
#include <hip/hip_runtime.h>
#include <math.h>

#define FIN 35
#define F1  64

// ---------- init: cnt=0, deg=1 (self-loop weight) ----------
__global__ void k_init(int* cnt, float* deg, int n) {
    int i = blockIdx.x * blockDim.x + threadIdx.x;
    if (i < n) { cnt[i] = 0; deg[i] = 1.0f; }
}

// ---------- per-dst edge count + weighted degree (atomics stay L2-resident: 400KB) ----------
__global__ void k_count(const int* __restrict__ dst, const float* __restrict__ ew,
                        int* cnt, float* deg, int E) {
    int e = blockIdx.x * blockDim.x + threadIdx.x;
    if (e < E) {
        int d = dst[e];
        atomicAdd(&cnt[d], 1);
        atomicAdd(&deg[d], ew[e]);
    }
}

// ---------- scan stage 1: block-local inclusive scan of cnt; block totals to bsum ----------
__global__ void k_scan1(const int* __restrict__ cnt, int* row_ptr, int* bsum, int n) {
    __shared__ int s[256];
    int t = threadIdx.x;
    int i = blockIdx.x * 256 + t;
    int v = (i < n) ? cnt[i] : 0;
    s[t] = v;
    __syncthreads();
    #pragma unroll
    for (int off = 1; off < 256; off <<= 1) {
        int tv = (t >= off) ? s[t - off] : 0;
        __syncthreads();
        s[t] += tv;
        __syncthreads();
    }
    if (i < n) row_ptr[i + 1] = s[t];          // block-local inclusive; offset added in scan3
    if (t == 255) bsum[blockIdx.x] = s[255];
}

// ---------- scan stage 2: single-block exclusive scan of block totals (nb <= 1024) ----------
__global__ void k_scan2(int* bsum, int nb) {
    __shared__ int s[1024];
    int t = threadIdx.x;
    int v = (t < nb) ? bsum[t] : 0;
    s[t] = v;
    __syncthreads();
    #pragma unroll
    for (int off = 1; off < 1024; off <<= 1) {
        int tv = (t >= off) ? s[t - off] : 0;
        __syncthreads();
        s[t] += tv;
        __syncthreads();
    }
    if (t < nb) bsum[t] = s[t] - v;            // exclusive
}

// ---------- scan stage 3: add block offsets; derive fill counters; deg -> dinv ----------
__global__ void k_scan3(const int* __restrict__ cnt, int* row_ptr, const int* __restrict__ bsum,
                        int* fill, float* deg, int n) {
    int i = blockIdx.x * blockDim.x + threadIdx.x;
    if (i >= n) return;
    int v = row_ptr[i + 1] + bsum[i >> 8];
    row_ptr[i + 1] = v;
    fill[i] = v - cnt[i];                      // = row_ptr[i] (start of node i's bucket)
    if (i == 0) row_ptr[0] = 0;
    deg[i] = rsqrtf(deg[i]);                   // deg >= 1 always (self-loop)
}

// ---------- fill CSR: bucket edges by dst ----------
__global__ void k_fill(const int* __restrict__ src, const int* __restrict__ dst,
                       const float* __restrict__ ew, int* fill,
                       int* csr_src, float* csr_w, int E) {
    int e = blockIdx.x * blockDim.x + threadIdx.x;
    if (e >= E) return;
    int d = dst[e];
    int pos = atomicAdd(&fill[d], 1);
    csr_src[pos] = src[e];
    csr_w[pos] = ew[e];
}

// ---------- layer 1 GEMM: g1[row,f] = dinv[row] * sum_k x[row,k]*W1[k,f] ----------
__global__ void k_gemm1(const float* __restrict__ x, const float* __restrict__ W1,
                        const float* __restrict__ dinv, float* __restrict__ g1, int n) {
    __shared__ float W1s[FIN * F1];
    __shared__ float xs[4 * FIN];
    int tid = threadIdx.x;
    for (int i = tid; i < FIN * F1; i += 256) W1s[i] = W1[i];
    int row0 = blockIdx.x * 4;
    int nrows = min(4, n - row0);
    if (tid < nrows * FIN) xs[tid] = x[(size_t)row0 * FIN + tid];
    __syncthreads();
    int rl = tid >> 6;
    int f  = tid & 63;
    if (rl < nrows) {
        float acc = 0.0f;
        #pragma unroll
        for (int k = 0; k < FIN; k++) acc += xs[rl * FIN + k] * W1s[k * F1 + f];
        int row = row0 + rl;
        g1[(size_t)row * F1 + f] = acc * dinv[row];
    }
}

// ---------- fused: layer-1 gather + ReLU + layer-2 GEMM (64->2); h stays in registers ----------
__global__ void k_gather1(const int* __restrict__ rp, const int* __restrict__ csr_src,
                          const float* __restrict__ csr_w, const float* __restrict__ g1,
                          const float* __restrict__ dinv, const float* __restrict__ b1,
                          const float* __restrict__ W2, float* __restrict__ g2, int n) {
    int wid = (int)((blockIdx.x * (long long)blockDim.x + threadIdx.x) >> 6);
    int f = threadIdx.x & 63;
    if (wid >= n) return;
    int start = rp[wid], end = rp[wid + 1];
    float acc = 0.0f;
    int e = start;
    for (; e + 4 <= end; e += 4) {             // 4-way ILP on the gather loads
        int   s0 = csr_src[e], s1 = csr_src[e+1], s2 = csr_src[e+2], s3 = csr_src[e+3];
        float w0 = csr_w[e],  w1 = csr_w[e+1],  w2 = csr_w[e+2],  w3 = csr_w[e+3];
        float a0 = g1[(size_t)s0 * F1 + f];
        float a1 = g1[(size_t)s1 * F1 + f];
        float a2 = g1[(size_t)s2 * F1 + f];
        float a3 = g1[(size_t)s3 * F1 + f];
        acc += w0 * a0; acc += w1 * a1; acc += w2 * a2; acc += w3 * a3;
    }
    for (; e < end; e++) acc += csr_w[e] * g1[(size_t)csr_src[e] * F1 + f];
    float dv = dinv[wid];
    float h = dv * (acc + g1[(size_t)wid * F1 + f]) + b1[f];   // +g1[v]: self-loop (w=1)
    h = h > 0.0f ? h : 0.0f;
    float2 w2v = ((const float2*)W2)[f];
    float z0 = h * w2v.x, z1 = h * w2v.y;
    #pragma unroll
    for (int off = 32; off > 0; off >>= 1) {
        z0 += __shfl_xor(z0, off, 64);
        z1 += __shfl_xor(z1, off, 64);
    }
    if (f == 0) {
        g2[(size_t)wid * 2 + 0] = dv * z0;
        g2[(size_t)wid * 2 + 1] = dv * z1;
    }
}

// ---------- fused: layer-2 gather + bias + log_softmax ----------
__global__ void k_gather2(const int* __restrict__ rp, const int* __restrict__ csr_src,
                          const float* __restrict__ csr_w, const float* __restrict__ g2,
                          const float* __restrict__ dinv, const float* __restrict__ b2,
                          float* __restrict__ out, int n) {
    int wid = (int)((blockIdx.x * (long long)blockDim.x + threadIdx.x) >> 6);
    int lane = threadIdx.x & 63;
    if (wid >= n) return;
    int start = rp[wid], end = rp[wid + 1];
    float a0 = 0.0f, a1 = 0.0f;
    for (int e = start + lane; e < end; e += 64) {   // coalesced csr reads
        int s = csr_src[e];
        float w = csr_w[e];
        float2 gv = ((const float2*)g2)[s];
        a0 += w * gv.x; a1 += w * gv.y;
    }
    #pragma unroll
    for (int off = 32; off > 0; off >>= 1) {
        a0 += __shfl_xor(a0, off, 64);
        a1 += __shfl_xor(a1, off, 64);
    }
    if (lane == 0) {
        float dv = dinv[wid];
        float2 sv = ((const float2*)g2)[wid];        // self-loop
        float z0 = dv * (a0 + sv.x) + b2[0];
        float z1 = dv * (a1 + sv.y) + b2[1];
        float m = fmaxf(z0, z1);
        float lse = m + logf(expf(z0 - m) + expf(z1 - m));
        ((float2*)out)[wid] = make_float2(z0 - lse, z1 - lse);
    }
}

extern "C" void kernel_launch(void* const* d_in, const int* in_sizes, int n_in,
                              void* d_out, int out_size, void* d_ws, size_t ws_size,
                              hipStream_t stream) {
    const float* x  = (const float*)d_in[0];
    const int*   ei = (const int*)d_in[1];    // [2, E]: src row then dst row
    const float* ew = (const float*)d_in[2];
    const float* W1 = (const float*)d_in[3];
    const float* b1 = (const float*)d_in[4];
    const float* W2 = (const float*)d_in[5];
    const float* b2 = (const float*)d_in[6];
    float* out = (float*)d_out;

    int n = in_sizes[0] / FIN;
    int E = in_sizes[2];
    const int* src = ei;
    const int* dst = ei + E;

    // workspace carve-out, 16B-aligned slices
    char* ws = (char*)d_ws;
    size_t off = 0;
    auto alloc = [&](size_t bytes) -> void* {
        void* p = ws + off;
        off += (bytes + 15) & ~(size_t)15;
        return p;
    };
    int*   cnt     = (int*)  alloc((size_t)n * 4);
    int*   row_ptr = (int*)  alloc((size_t)(n + 1) * 4);
    int*   fill    = (int*)  alloc((size_t)n * 4);
    int*   bsum    = (int*)  alloc(1024 * 4);
    float* deg     = (float*)alloc((size_t)n * 4);       // becomes dinv after scan3
    int*   csr_src = (int*)  alloc((size_t)E * 4);
    float* csr_w   = (float*)alloc((size_t)E * 4);
    float* g1      = (float*)alloc((size_t)n * F1 * 4);
    float* g2      = (float*)alloc((size_t)n * 2 * 4);

    int nb = (n + 255) / 256;   // 391 for n=100000; k_scan2 handles nb <= 1024

    k_init <<<(n + 255) / 256, 256, 0, stream>>>(cnt, deg, n);
    k_count<<<(E + 255) / 256, 256, 0, stream>>>(dst, ew, cnt, deg, E);
    k_scan1<<<nb, 256, 0, stream>>>(cnt, row_ptr, bsum, n);
    k_scan2<<<1, 1024, 0, stream>>>(bsum, nb);
    k_scan3<<<nb, 256, 0, stream>>>(cnt, row_ptr, bsum, fill, deg, n);
    k_fill <<<(E + 255) / 256, 256, 0, stream>>>(src, dst, ew, fill, csr_src, csr_w, E);

    k_gemm1  <<<(n + 3) / 4, 256, 0, stream>>>(x, W1, deg, g1, n);
    k_gather1<<<(n + 3) / 4, 256, 0, stream>>>(row_ptr, csr_src, csr_w, g1, deg, b1, W2, g2, n);
    k_gather2<<<(n + 3) / 4, 256, 0, stream>>>(row_ptr, csr_src, csr_w, g2, deg, b2, out, n);
}

// Round 3
// 796.858 us; speedup vs baseline: 4.0164x; 1.0827x over previous
//
#include <hip/hip_runtime.h>
#include <hip/hip_fp16.h>
#include <math.h>

#define FIN 35
#define F1  64

// ---------- init: cnt=0, deg=1 (self-loop weight) ----------
__global__ void k_init(int* cnt, float* deg, int n) {
    int i = blockIdx.x * blockDim.x + threadIdx.x;
    if (i < n) { cnt[i] = 0; deg[i] = 1.0f; }
}

// ---------- per-dst edge count + weighted degree (atomics on 800KB, L2-resident) ----------
__global__ void k_count(const int* __restrict__ dst, const float* __restrict__ ew,
                        int* cnt, float* deg, int E) {
    int e = blockIdx.x * blockDim.x + threadIdx.x;
    if (e < E) {
        int d = dst[e];
        atomicAdd(&cnt[d], 1);
        atomicAdd(&deg[d], ew[e]);
    }
}

// ---------- scan stage 1: block-local inclusive scan of cnt; block totals to bsum ----------
__global__ void k_scan1(const int* __restrict__ cnt, int* row_ptr, int* bsum, int n) {
    __shared__ int s[256];
    int t = threadIdx.x;
    int i = blockIdx.x * 256 + t;
    int v = (i < n) ? cnt[i] : 0;
    s[t] = v;
    __syncthreads();
    #pragma unroll
    for (int off = 1; off < 256; off <<= 1) {
        int tv = (t >= off) ? s[t - off] : 0;
        __syncthreads();
        s[t] += tv;
        __syncthreads();
    }
    if (i < n) row_ptr[i + 1] = s[t];          // block-local inclusive; offset added in scan3
    if (t == 255) bsum[blockIdx.x] = s[255];
}

// ---------- scan stage 2: single-block exclusive scan of block totals (nb <= 1024) ----------
__global__ void k_scan2(int* bsum, int nb) {
    __shared__ int s[1024];
    int t = threadIdx.x;
    int v = (t < nb) ? bsum[t] : 0;
    s[t] = v;
    __syncthreads();
    #pragma unroll
    for (int off = 1; off < 1024; off <<= 1) {
        int tv = (t >= off) ? s[t - off] : 0;
        __syncthreads();
        s[t] += tv;
        __syncthreads();
    }
    if (t < nb) bsum[t] = s[t] - v;            // exclusive
}

// ---------- scan stage 3: add block offsets; derive fill counters; deg -> dinv ----------
__global__ void k_scan3(const int* __restrict__ cnt, int* row_ptr, const int* __restrict__ bsum,
                        int* fill, float* deg, int n) {
    int i = blockIdx.x * blockDim.x + threadIdx.x;
    if (i >= n) return;
    int v = row_ptr[i + 1] + bsum[i >> 8];
    row_ptr[i + 1] = v;
    fill[i] = v - cnt[i];                      // = row_ptr[i] (start of node i's bucket)
    if (i == 0) row_ptr[0] = 0;
    deg[i] = rsqrtf(deg[i]);                   // deg >= 1 always (self-loop)
}

// ---------- fill CSR: bucket edges by dst; ONE 8B record per edge ----------
__global__ void k_fill(const int* __restrict__ src, const int* __restrict__ dst,
                       const float* __restrict__ ew, int* fill,
                       int2* __restrict__ csr, int E) {
    int e = blockIdx.x * blockDim.x + threadIdx.x;
    if (e >= E) return;
    int d = dst[e];
    int pos = atomicAdd(&fill[d], 1);
    csr[pos] = make_int2(src[e], __float_as_int(ew[e]));
}

// ---------- layer 1 GEMM: g1[row,f] = fp16( dinv[row] * sum_k x[row,k]*W1[k,f] ) ----------
__global__ void k_gemm1(const float* __restrict__ x, const float* __restrict__ W1,
                        const float* __restrict__ dinv, __half* __restrict__ g1, int n) {
    __shared__ float W1s[FIN * F1];
    __shared__ float xs[4 * FIN];
    int tid = threadIdx.x;
    for (int i = tid; i < FIN * F1; i += 256) W1s[i] = W1[i];
    int row0 = blockIdx.x * 4;
    int nrows = min(4, n - row0);
    if (tid < nrows * FIN) xs[tid] = x[(size_t)row0 * FIN + tid];
    __syncthreads();
    int rl = tid >> 6;
    int f  = tid & 63;
    if (rl < nrows) {
        float acc = 0.0f;
        #pragma unroll
        for (int k = 0; k < FIN; k++) acc += xs[rl * FIN + k] * W1s[k * F1 + f];
        int row = row0 + rl;
        g1[(size_t)row * F1 + f] = __float2half(acc * dinv[row]);
    }
}

// ---------- fused: layer-1 gather (fp16 rows) + ReLU + layer-2 GEMM (64->2) ----------
// one wave per node; lane = feature. h never touches memory.
__global__ void k_gather1(const int* __restrict__ rp, const int2* __restrict__ csr,
                          const __half* __restrict__ g1,
                          const float* __restrict__ dinv, const float* __restrict__ b1,
                          const float* __restrict__ W2, float* __restrict__ g2, int n) {
    int wid = (int)((blockIdx.x * (long long)blockDim.x + threadIdx.x) >> 6);
    int f = threadIdx.x & 63;
    if (wid >= n) return;
    int start = rp[wid], end = rp[wid + 1];
    float acc = 0.0f;
    int e = start;
    for (; e + 4 <= end; e += 4) {             // 4-way ILP on the gather loads
        int2 r0 = csr[e], r1 = csr[e+1], r2 = csr[e+2], r3 = csr[e+3];
        float a0 = __half2float(g1[(size_t)r0.x * F1 + f]);
        float a1 = __half2float(g1[(size_t)r1.x * F1 + f]);
        float a2 = __half2float(g1[(size_t)r2.x * F1 + f]);
        float a3 = __half2float(g1[(size_t)r3.x * F1 + f]);
        acc += __int_as_float(r0.y) * a0;
        acc += __int_as_float(r1.y) * a1;
        acc += __int_as_float(r2.y) * a2;
        acc += __int_as_float(r3.y) * a3;
    }
    for (; e < end; e++) {
        int2 r = csr[e];
        acc += __int_as_float(r.y) * __half2float(g1[(size_t)r.x * F1 + f]);
    }
    float dv = dinv[wid];
    float h = dv * (acc + __half2float(g1[(size_t)wid * F1 + f])) + b1[f]; // self-loop w=1
    h = h > 0.0f ? h : 0.0f;
    float2 w2v = ((const float2*)W2)[f];
    float z0 = h * w2v.x, z1 = h * w2v.y;
    #pragma unroll
    for (int off = 32; off > 0; off >>= 1) {
        z0 += __shfl_xor(z0, off, 64);
        z1 += __shfl_xor(z1, off, 64);
    }
    if (f == 0) {
        g2[(size_t)wid * 2 + 0] = dv * z0;
        g2[(size_t)wid * 2 + 1] = dv * z1;
    }
}

// ---------- fused: layer-2 gather + bias + log_softmax ----------
__global__ void k_gather2(const int* __restrict__ rp, const int2* __restrict__ csr,
                          const float* __restrict__ g2,
                          const float* __restrict__ dinv, const float* __restrict__ b2,
                          float* __restrict__ out, int n) {
    int wid = (int)((blockIdx.x * (long long)blockDim.x + threadIdx.x) >> 6);
    int lane = threadIdx.x & 63;
    if (wid >= n) return;
    int start = rp[wid], end = rp[wid + 1];
    float a0 = 0.0f, a1 = 0.0f;
    for (int e = start + lane; e < end; e += 64) {   // coalesced csr reads
        int2 r = csr[e];
        float w = __int_as_float(r.y);
        float2 gv = ((const float2*)g2)[r.x];
        a0 += w * gv.x; a1 += w * gv.y;
    }
    #pragma unroll
    for (int off = 32; off > 0; off >>= 1) {
        a0 += __shfl_xor(a0, off, 64);
        a1 += __shfl_xor(a1, off, 64);
    }
    if (lane == 0) {
        float dv = dinv[wid];
        float2 sv = ((const float2*)g2)[wid];        // self-loop
        float z0 = dv * (a0 + sv.x) + b2[0];
        float z1 = dv * (a1 + sv.y) + b2[1];
        float m = fmaxf(z0, z1);
        float lse = m + logf(expf(z0 - m) + expf(z1 - m));
        ((float2*)out)[wid] = make_float2(z0 - lse, z1 - lse);
    }
}

extern "C" void kernel_launch(void* const* d_in, const int* in_sizes, int n_in,
                              void* d_out, int out_size, void* d_ws, size_t ws_size,
                              hipStream_t stream) {
    const float* x  = (const float*)d_in[0];
    const int*   ei = (const int*)d_in[1];    // [2, E]: src row then dst row
    const float* ew = (const float*)d_in[2];
    const float* W1 = (const float*)d_in[3];
    const float* b1 = (const float*)d_in[4];
    const float* W2 = (const float*)d_in[5];
    const float* b2 = (const float*)d_in[6];
    float* out = (float*)d_out;

    int n = in_sizes[0] / FIN;
    int E = in_sizes[2];
    const int* src = ei;
    const int* dst = ei + E;

    // workspace carve-out, 16B-aligned slices
    char* ws = (char*)d_ws;
    size_t off = 0;
    auto alloc = [&](size_t bytes) -> void* {
        void* p = ws + off;
        off += (bytes + 15) & ~(size_t)15;
        return p;
    };
    int*    cnt     = (int*)   alloc((size_t)n * 4);
    int*    row_ptr = (int*)   alloc((size_t)(n + 1) * 4);
    int*    fill    = (int*)   alloc((size_t)n * 4);
    int*    bsum    = (int*)   alloc(1024 * 4);
    float*  deg     = (float*) alloc((size_t)n * 4);      // becomes dinv after scan3
    int2*   csr     = (int2*)  alloc((size_t)E * 8);      // packed {src, w}
    __half* g1      = (__half*)alloc((size_t)n * F1 * 2); // fp16 table: 12.8 MB
    float*  g2      = (float*) alloc((size_t)n * 2 * 4);

    int nb = (n + 255) / 256;   // 391 for n=100000; k_scan2 handles nb <= 1024

    k_init <<<(n + 255) / 256, 256, 0, stream>>>(cnt, deg, n);
    k_count<<<(E + 255) / 256, 256, 0, stream>>>(dst, ew, cnt, deg, E);
    k_scan1<<<nb, 256, 0, stream>>>(cnt, row_ptr, bsum, n);
    k_scan2<<<1, 1024, 0, stream>>>(bsum, nb);
    k_scan3<<<nb, 256, 0, stream>>>(cnt, row_ptr, bsum, fill, deg, n);
    k_fill <<<(E + 255) / 256, 256, 0, stream>>>(src, dst, ew, fill, csr, E);

    k_gemm1  <<<(n + 3) / 4, 256, 0, stream>>>(x, W1, deg, g1, n);
    k_gather1<<<(n + 3) / 4, 256, 0, stream>>>(row_ptr, csr, g1, deg, b1, W2, g2, n);
    k_gather2<<<(n + 3) / 4, 256, 0, stream>>>(row_ptr, csr, g2, deg, b2, out, n);
}